// Round 15
// baseline (534.629 us; speedup 1.0000x reference)
//
#include <hip/hip_runtime.h>

// PVDST semseg, MI355X/gfx950. FP32 I/O. Round-15: polish.
//   - knn_p2: contracted-fma distance prefilter (slack 1e-3 >> fma-vs-_rn
//     error), exact _rn recompute + original d<=th test inside -> identical
//     qualifying set, ~10 instr/cand amortized (was ~13).
//   - attn: idx row loaded as 4x int4 (64B-aligned) instead of 16 scalars.
//   - knn_mrg block 256.
// Rest identical to R14 (passed, absmax 1.95e-3).

#define NB 4
#define NP 4096
#define NT 16384   // NB*NP tokens

#define SCRATCH_BYTES (132u*1024u*1024u)
__device__ __align__(256) unsigned char g_scratch[SCRATCH_BYTES];

typedef __attribute__((ext_vector_type(8))) short short8;   // 8 x bf16 MFMA frag
typedef __attribute__((ext_vector_type(4))) float f32x4;    // MFMA acc
typedef __attribute__((ext_vector_type(4))) unsigned short ushort4v;

__device__ __forceinline__ float bf2f(unsigned short u){
  unsigned int v = ((unsigned int)u) << 16;
  return __builtin_bit_cast(float, v);
}
__device__ __forceinline__ unsigned short f2bf(float f){
  unsigned int x = __builtin_bit_cast(unsigned int, f);
  x += 0x7fffu + ((x >> 16) & 1u);     // RNE
  return (unsigned short)(x >> 16);
}
// numpy-matched: ((x*x)+(y*y))+(z*z), each op rounded (no fma contraction)
__device__ __forceinline__ float sq3(float x, float y, float z){
  return __fadd_rn(__fadd_rn(__fmul_rn(x,x), __fmul_rn(y,y)), __fmul_rn(z,z));
}

// sorted-4 insert: 7 native min/max, no masks
#define KINS4(a0,a1,a2,a3,dd) do{ float _d=(dd);\
  a3=fminf(fmaxf(a2,_d),a3); a2=fminf(fmaxf(a1,_d),a2);\
  a1=fminf(fmaxf(a0,_d),a1); a0=fminf(a0,_d);}while(0)

// dist-only sorted-ascending top-16 (thr kernel)
#define KDECLD float d0=3.0e38f,d1=3.0e38f,d2=3.0e38f,d3=3.0e38f,d4=3.0e38f,\
  d5=3.0e38f,d6=3.0e38f,d7=3.0e38f,d8=3.0e38f,d9=3.0e38f,d10=3.0e38f,\
  d11=3.0e38f,d12=3.0e38f,d13=3.0e38f,d14=3.0e38f,d15=3.0e38f
#define KINSD(dd) do{ float _d=(dd); \
  d15=fminf(fmaxf(d14,_d),d15); d14=fminf(fmaxf(d13,_d),d14); \
  d13=fminf(fmaxf(d12,_d),d13); d12=fminf(fmaxf(d11,_d),d12); \
  d11=fminf(fmaxf(d10,_d),d11); d10=fminf(fmaxf(d9 ,_d),d10); \
  d9 =fminf(fmaxf(d8 ,_d),d9 ); d8 =fminf(fmaxf(d7 ,_d),d8 ); \
  d7 =fminf(fmaxf(d6 ,_d),d7 ); d6 =fminf(fmaxf(d5 ,_d),d6 ); \
  d5 =fminf(fmaxf(d4 ,_d),d5 ); d4 =fminf(fmaxf(d3 ,_d),d4 ); \
  d3 =fminf(fmaxf(d2 ,_d),d3 ); d2 =fminf(fmaxf(d1 ,_d),d2 ); \
  d1 =fminf(fmaxf(d0 ,_d),d1 ); d0 =fminf(d0,_d); }while(0)

// full (dist,idx) stable insert (merge only; strict < => lower index wins)
#define KDECL KDECLD; int i0=0,i1=0,i2=0,i3=0,i4=0,i5=0,i6=0,i7=0,i8=0,\
  i9=0,i10=0,i11=0,i12=0,i13=0,i14=0,i15=0
#define KINS(dd,mm) do{ float _d=(dd); int _m=(mm); \
  bool c15 = _d < d15; \
  bool c14 = _d < d14;  i15 = c14 ? i14 : (c15 ? _m : i15);  d15 = fminf(fmaxf(d14,_d), d15); \
  bool c13 = _d < d13;  i14 = c13 ? i13 : (c14 ? _m : i14);  d14 = fminf(fmaxf(d13,_d), d14); \
  bool c12 = _d < d12;  i13 = c12 ? i12 : (c13 ? _m : i13);  d13 = fminf(fmaxf(d12,_d), d13); \
  bool c11 = _d < d11;  i12 = c11 ? i11 : (c12 ? _m : i12);  d12 = fminf(fmaxf(d11,_d), d12); \
  bool c10 = _d < d10;  i11 = c10 ? i10 : (c11 ? _m : i11);  d11 = fminf(fmaxf(d10,_d), d11); \
  bool c9  = _d < d9;   i10 = c9  ? i9  : (c10 ? _m : i10);  d10 = fminf(fmaxf(d9 ,_d), d10); \
  bool c8  = _d < d8;   i9  = c8  ? i8  : (c9  ? _m : i9 );  d9  = fminf(fmaxf(d8 ,_d), d9 ); \
  bool c7  = _d < d7;   i8  = c7  ? i7  : (c8  ? _m : i8 );  d8  = fminf(fmaxf(d7 ,_d), d8 ); \
  bool c6  = _d < d6;   i7  = c6  ? i6  : (c7  ? _m : i7 );  d7  = fminf(fmaxf(d6 ,_d), d7 ); \
  bool c5  = _d < d5;   i6  = c5  ? i5  : (c6  ? _m : i6 );  d6  = fminf(fmaxf(d5 ,_d), d6 ); \
  bool c4  = _d < d4;   i5  = c4  ? i4  : (c5  ? _m : i5 );  d5  = fminf(fmaxf(d4 ,_d), d5 ); \
  bool c3  = _d < d3;   i4  = c3  ? i3  : (c4  ? _m : i4 );  d4  = fminf(fmaxf(d3 ,_d), d4 ); \
  bool c2  = _d < d2;   i3  = c2  ? i2  : (c3  ? _m : i3 );  d3  = fminf(fmaxf(d2 ,_d), d3 ); \
  bool c1  = _d < d1;   i2  = c1  ? i1  : (c2  ? _m : i2 );  d2  = fminf(fmaxf(d1 ,_d), d2 ); \
  bool c0  = _d < d0;   i1  = c0  ? i0  : (c1  ? _m : i1 );  d1  = fminf(fmaxf(d0 ,_d), d1 ); \
  i0 = c0 ? _m : i0;  d0 = fminf(d0,_d); }while(0)

// ---------------- fused weight fp32 -> bf16 conversion prepass ----------------
struct CvtArgs {
  const float* src[8];
  unsigned dstOff[8];
  int n[8];
};
__global__ __launch_bounds__(256) void cvt_all(CvtArgs a)
{
  int y = blockIdx.y;
  const float* src = a.src[y];
  unsigned short* dst = (unsigned short*)(g_scratch + a.dstOff[y]);
  int n = a.n[y];
  if (y == 7){
    for (int i = blockIdx.x*256 + threadIdx.x; i < n; i += gridDim.x*256){
      int r = i >> 10, c = i & 1023;
      dst[i] = f2bf(src[(size_t)r*3072 + c]);
    }
  } else {
    for (int i = blockIdx.x*256 + threadIdx.x; i < n; i += gridDim.x*256)
      dst[i] = f2bf(src[i]);
  }
}

// ---------------- KNN pass1: 4x sorted-4 bound lists, fma dist ----------------
__global__ __launch_bounds__(256) void knn_p1(const float* __restrict__ in,
                                              unsigned pdOff)
{
  float* pdist = (float*)(g_scratch + pdOff);
  __shared__ float4 sp[256];
  int b = blockIdx.z, qc = blockIdx.x, cc = blockIdx.y;
  const float* xb = in + (size_t)b*9*NP;
  int base = cc*256;
  {
    int i = threadIdx.x;
    float x = xb[base+i], y = xb[NP+base+i], z = xb[2*NP+base+i];
    sp[i] = make_float4(x,y,z, x*x+y*y+z*z);
  }
  __syncthreads();
  int n = qc*256 + threadIdx.x;
  float xn=xb[n], yn=xb[NP+n], zn=xb[2*NP+n];
  float sqn = xn*xn + yn*yn + zn*zn;
  float A0=3e38f,A1=3e38f,A2=3e38f,A3=3e38f;
  float B0=3e38f,B1=3e38f,B2=3e38f,B3=3e38f;
  float C0=3e38f,C1=3e38f,C2=3e38f,C3=3e38f;
  float D0=3e38f,D1=3e38f,D2=3e38f,D3=3e38f;
  for (int mm=0; mm<256; mm+=4){
    float4 p0 = sp[mm], p1 = sp[mm+1], p2 = sp[mm+2], p3 = sp[mm+3];
    float e0 = sqn + p0.w - 2.f*(xn*p0.x + yn*p0.y + zn*p0.z);
    float e1 = sqn + p1.w - 2.f*(xn*p1.x + yn*p1.y + zn*p1.z);
    float e2 = sqn + p2.w - 2.f*(xn*p2.x + yn*p2.y + zn*p2.z);
    float e3 = sqn + p3.w - 2.f*(xn*p3.x + yn*p3.y + zn*p3.z);
    KINS4(A0,A1,A2,A3,e0);
    KINS4(B0,B1,B2,B3,e1);
    KINS4(C0,C1,C2,C3,e2);
    KINS4(D0,D1,D2,D3,e3);
  }
  size_t ob = ((size_t)(b*16+cc)*16)*NP + n;
  pdist[ob+ 0*(size_t)NP]=A0; pdist[ob+ 1*(size_t)NP]=A1; pdist[ob+ 2*(size_t)NP]=A2; pdist[ob+ 3*(size_t)NP]=A3;
  pdist[ob+ 4*(size_t)NP]=B0; pdist[ob+ 5*(size_t)NP]=B1; pdist[ob+ 6*(size_t)NP]=B2; pdist[ob+ 7*(size_t)NP]=B3;
  pdist[ob+ 8*(size_t)NP]=C0; pdist[ob+ 9*(size_t)NP]=C1; pdist[ob+10*(size_t)NP]=C2; pdist[ob+11*(size_t)NP]=C3;
  pdist[ob+12*(size_t)NP]=D0; pdist[ob+13*(size_t)NP]=D1; pdist[ob+14*(size_t)NP]=D2; pdist[ob+15*(size_t)NP]=D3;
}

// ---------------- KNN thr: 16th-smallest of the 256 bound values + margin ----
__global__ __launch_bounds__(256) void knn_thr(unsigned pdOff, unsigned thrOff)
{
  const float* pdist = (const float*)(g_scratch + pdOff);
  float* thr = (float*)(g_scratch + thrOff);
  int t = blockIdx.x*256 + threadIdx.x;
  int b = t >> 12, n = t & 4095;
  KDECLD;
  for (int cc=0; cc<16; ++cc){
    size_t ob = ((size_t)(b*16+cc)*16)*NP + n;
    #pragma unroll
    for (int j=0;j<16;j++){ KINSD(pdist[ob + (size_t)j*NP]); }
  }
  thr[t] = d15*1.000002f + 2e-4f;   // margin >> fma-vs-_rn error
}

// ---------------- KNN pass2: fma prefilter + exact _rn qualify --------
__global__ __launch_bounds__(256) void knn_p2(const float* __restrict__ in,
                                              unsigned thrOff, unsigned pdOff, unsigned piOff)
{
  const float* thr = (const float*)(g_scratch + thrOff);
  float* pdist = (float*)(g_scratch + pdOff);
  int*   pidx  = (int*)  (g_scratch + piOff);
  __shared__ float4 sp[256];
  int b = blockIdx.z, qc = blockIdx.x, cc = blockIdx.y;
  const float* xb = in + (size_t)b*9*NP;
  int base = cc*256;
  {
    int i = threadIdx.x;
    float x = xb[base+i], y = xb[NP+base+i], z = xb[2*NP+base+i];
    sp[i] = make_float4(x,y,z,sq3(x,y,z));
  }
  __syncthreads();
  int n = qc*256 + threadIdx.x;
  float xn=xb[n], yn=xb[NP+n], zn=xb[2*NP+n];
  float sqn = sq3(xn,yn,zn);
  float th = thr[(b<<12) + n];
  float thx = th*1.000001f + 1e-3f;   // prefilter slack >= |d_fma - d_rn|
  size_t o = ((size_t)((b*16 + cc)*NP + n))*16;
  int cnt = 0;
  for (int mm=0; mm<256; ++mm){
    float4 p = sp[mm];
    float dfma = sqn + p.w - 2.f*(xn*p.x + yn*p.y + zn*p.z);  // contracted
    if (dfma <= thx && cnt < 16){
      // exact numpy-rounded distance; original qualifying test preserved
      float dot = __fadd_rn(__fadd_rn(__fmul_rn(xn,p.x), __fmul_rn(yn,p.y)), __fmul_rn(zn,p.z));
      float d = __fsub_rn(__fadd_rn(sqn, p.w), __fmul_rn(2.0f, dot));
      if (d <= th){
        pdist[o+cnt] = d;
        pidx[o+cnt] = base + mm;
        cnt++;
      }
    }
  }
  if (cnt < 16) pdist[o+cnt] = 3.0e38f;   // sentinel terminator
}

// ---------------- KNN final merge (index-ordered sparse lists) ----------------
__global__ __launch_bounds__(256) void knn_mrg(unsigned pdOff, unsigned piOff, unsigned idxOff)
{
  const float* pdist = (const float*)(g_scratch + pdOff);
  const int*   pidx  = (const int*)  (g_scratch + piOff);
  int*         idxOut= (int*)(g_scratch + idxOff);
  int t = blockIdx.x*256 + threadIdx.x;
  int b = t >> 12, n = t & 4095;
  KDECL;
  for (int cc=0; cc<16; ++cc){
    size_t o = ((size_t)((b*16 + cc)*NP + n))*16;
    #pragma unroll 1
    for (int j=0;j<16;j++){
      float pd = pdist[o+j];
      if (pd >= 1.0e38f) break;          // sentinel
      KINS(pd, pidx[o+j]);
    }
  }
  idxOut[t*16+ 0]=i0;  idxOut[t*16+ 1]=i1;  idxOut[t*16+ 2]=i2;  idxOut[t*16+ 3]=i3;
  idxOut[t*16+ 4]=i4;  idxOut[t*16+ 5]=i5;  idxOut[t*16+ 6]=i6;  idxOut[t*16+ 7]=i7;
  idxOut[t*16+ 8]=i8;  idxOut[t*16+ 9]=i9;  idxOut[t*16+10]=i10; idxOut[t*16+11]=i11;
  idxOut[t*16+12]=i12; idxOut[t*16+13]=i13; idxOut[t*16+14]=i14; idxOut[t*16+15]=i15;
}

// ---------------- embedding conv1 (Cin=9), output-split ----------------
__global__ __launch_bounds__(256) void emb1_kernel(const float* __restrict__ in,
                                                   const float* __restrict__ w1,
                                                   const float* __restrict__ s1,
                                                   const float* __restrict__ b1,
                                                   unsigned x1Off)
{
  unsigned short* x1 = (unsigned short*)(g_scratch + x1Off);
  int og = blockIdx.y*32;
  __shared__ float wf[32*9], sf[32], bf_[32];
  for (int i = threadIdx.x; i < 32*9; i += 256) wf[i] = w1[og*9 + i];
  if (threadIdx.x < 32){ sf[threadIdx.x]=s1[og+threadIdx.x]; bf_[threadIdx.x]=b1[og+threadIdx.x]; }
  __syncthreads();
  int t = blockIdx.x*256 + threadIdx.x;
  int b = t >> 12, n = t & 4095;
  float v[9];
  #pragma unroll
  for (int c=0;c<9;c++) v[c] = in[((size_t)b*9 + c)*NP + n];
  for (int o=0;o<32;o+=2){
    float a0=0.f, a1=0.f;
    #pragma unroll
    for (int c=0;c<9;c++){ a0 += wf[o*9+c]*v[c]; a1 += wf[(o+1)*9+c]*v[c]; }
    a0 = fmaxf(sf[o]*a0 + bf_[o], 0.f);
    a1 = fmaxf(sf[o+1]*a1 + bf_[o+1], 0.f);
    unsigned pk = (unsigned)f2bf(a0) | ((unsigned)f2bf(a1) << 16);
    *(unsigned*)(x1 + (size_t)t*128 + og + o) = pk;
  }
}

// ---------------- GEMM epilogue (shared) ----------------
enum { EPI_PLAIN=0, EPI_RELU_SB=1, EPI_RES=2, EPI_LEAKY=3, EPI_CLS=4 };

template<int EPI, bool EXB>
__device__ __forceinline__ void gemm_epi(
    f32x4 (&acc)[4][4], int M0, int T0, int r, int q,
    unsigned short* out, int outStride, int outOff,
    const float* sPtr, const float* bPtr,
    const float* extraIn, unsigned extraOffB, int extraStride,
    unsigned resOffB, int resStride, int resOff)
{
  #pragma unroll
  for (int i=0;i<4;i++){
    int m = M0 + i*16 + q*4;
    float sv[4], bv[4];
    if constexpr (EPI != EPI_PLAIN){
      #pragma unroll
      for (int u=0;u<4;u++){ sv[u]=sPtr[m+u]; bv[u]=bPtr[m+u]; }
    }
    #pragma unroll
    for (int j=0;j<4;j++){
      int token = T0 + j*16 + r;
      float ex[4];
      if constexpr (EPI == EPI_CLS){
        int bb = token >> 12;
        #pragma unroll
        for (int u=0;u<4;u++)
          ex[u] = EXB ? extraIn[bb*extraStride + m + u]
                      : ((const float*)(g_scratch + extraOffB))[bb*extraStride + m + u];
      }
      float resv[4];
      if constexpr (EPI == EPI_RES){
        const unsigned short* resPtr = (const unsigned short*)(g_scratch + resOffB);
        ushort4v rv = *(const ushort4v*)(resPtr + (size_t)token*resStride + resOff + m);
        #pragma unroll
        for (int u=0;u<4;u++) resv[u]=bf2f(rv[u]);
      }
      ushort4v ov;
      #pragma unroll
      for (int u=0;u<4;u++){
        float aa = acc[i][j][u];
        float vo;
        if constexpr (EPI == EPI_PLAIN)        vo = aa;
        else if constexpr (EPI == EPI_RELU_SB) vo = fmaxf(sv[u]*aa + bv[u], 0.f);
        else if constexpr (EPI == EPI_RES)     vo = resv[u] + fmaxf(sv[u]*aa + bv[u], 0.f);
        else if constexpr (EPI == EPI_LEAKY){  float tt = sv[u]*aa + bv[u]; vo = tt>0.f ? tt : 0.2f*tt; }
        else { vo = fmaxf(sv[u]*(aa + ex[u]) + bv[u], 0.f); }
        ov[u] = f2bf(vo);
      }
      *(ushort4v*)(out + (size_t)token*outStride + outOff + m) = ov;
    }
  }
}

// ---------------- LDS-staged GEMM: 128Mx128T, BK=32 (fuse, cls1, cls2) -------
template<int EPI, bool EXB>
__global__ __launch_bounds__(256) void gemm_lds(
    unsigned W0off, unsigned W1off, unsigned W2off,
    unsigned O0off, unsigned O1off, unsigned O2off,
    unsigned XoffB, int Xstride, int Xoff,
    int outStride, int outOff,
    const float* sPtr, const float* bPtr,
    const float* extraIn, unsigned extraOffB, int extraStride,
    unsigned resOffB, int resStride, int resOff,
    int K, int Astride)
{
  __shared__ unsigned short As[128*32];
  __shared__ unsigned short Bs[128*32];
  const unsigned short* X = (const unsigned short*)(g_scratch + XoffB);
  unsigned wOffB   = (blockIdx.z==0) ? W0off : ((blockIdx.z==1) ? W1off : W2off);
  unsigned outOffB = (blockIdx.z==0) ? O0off : ((blockIdx.z==1) ? O1off : O2off);
  const unsigned short* W = (const unsigned short*)(g_scratch + wOffB);
  unsigned short* out = (unsigned short*)(g_scratch + outOffB);
  int lin = blockIdx.x + gridDim.x*blockIdx.y;
  int bx = lin >> 7;
  int by = (lin & 7)*16 + ((lin >> 3) & 15);
  int M0 = bx*128, T0 = by*128;
  int t = threadIdx.x;
  int lane = t & 63, wave = t >> 6;
  int r = lane & 15, q = lane >> 4;
  int srow = t >> 2, schunk = t & 3;

  const unsigned short* Ag0 = W + (size_t)(M0 + srow)*Astride + schunk*8;
  const unsigned short* Ag1 = W + (size_t)(M0 + 64 + srow)*Astride + schunk*8;
  const unsigned short* Bg0 = X + (size_t)(T0 + srow)*Xstride + Xoff + schunk*8;
  const unsigned short* Bg1 = X + (size_t)(T0 + 64 + srow)*Xstride + Xoff + schunk*8;
  unsigned short* Aw0 = &As[srow*32 + schunk*8];
  unsigned short* Aw1 = &As[(64 + srow)*32 + schunk*8];
  unsigned short* Bw0 = &Bs[srow*32 + schunk*8];
  unsigned short* Bw1 = &Bs[(64 + srow)*32 + schunk*8];

  int Mw = (wave>>1)*64, Tw = (wave&1)*64;
  f32x4 acc[4][4];
  #pragma unroll
  for (int i=0;i<4;i++)
    #pragma unroll
    for (int j=0;j<4;j++)
      #pragma unroll
      for (int u=0;u<4;u++) acc[i][j][u] = 0.f;

  for (int k0=0; k0<K; k0+=32){
    short8 va0 = *(const short8*)(Ag0 + k0);
    short8 va1 = *(const short8*)(Ag1 + k0);
    short8 vb0 = *(const short8*)(Bg0 + k0);
    short8 vb1 = *(const short8*)(Bg1 + k0);
    if (k0) __syncthreads();
    *(short8*)Aw0 = va0; *(short8*)Aw1 = va1;
    *(short8*)Bw0 = vb0; *(short8*)Bw1 = vb1;
    __syncthreads();
    short8 a[4], bfr[4];
    #pragma unroll
    for (int i=0;i<4;i++) a[i]   = *(const short8*)(&As[(Mw + i*16 + r)*32 + q*8]);
    #pragma unroll
    for (int j=0;j<4;j++) bfr[j] = *(const short8*)(&Bs[(Tw + j*16 + r)*32 + q*8]);
    #pragma unroll
    for (int i=0;i<4;i++)
      #pragma unroll
      for (int j=0;j<4;j++)
        acc[i][j] = __builtin_amdgcn_mfma_f32_16x16x32_bf16(a[i], bfr[j], acc[i][j], 0, 0, 0);
  }
  gemm_epi<EPI,EXB>(acc, M0+Mw, T0+Tw, r, q, out, outStride, outOff,
                    sPtr, bPtr, extraIn, extraOffB, extraStride,
                    resOffB, resStride, resOff);
}

// ---------------- LDS-staged 2-wave 64Mx128T (K=128 sites: emb2, qkv, wo) ----
template<int EPI, bool EXB>
__global__ __launch_bounds__(128) void gemm_small_lds(
    unsigned W0off, unsigned W1off, unsigned W2off,
    unsigned O0off, unsigned O1off, unsigned O2off,
    unsigned XoffB, int Xstride, int Xoff,
    int outStride, int outOff,
    const float* sPtr, const float* bPtr,
    const float* extraIn, unsigned extraOffB, int extraStride,
    unsigned resOffB, int resStride, int resOff,
    int K, int Astride)
{
  __shared__ unsigned short As[64*32];    // 4 KB
  __shared__ unsigned short Bs[128*32];   // 8 KB
  const unsigned short* X = (const unsigned short*)(g_scratch + XoffB);
  unsigned wOffB   = (blockIdx.z==0) ? W0off : ((blockIdx.z==1) ? W1off : W2off);
  unsigned outOffB = (blockIdx.z==0) ? O0off : ((blockIdx.z==1) ? O1off : O2off);
  const unsigned short* W = (const unsigned short*)(g_scratch + wOffB);
  unsigned short* out = (unsigned short*)(g_scratch + outOffB);
  int M0 = blockIdx.x*64, T0 = blockIdx.y*128;
  int t = threadIdx.x;
  int lane = t & 63, wave = t >> 6;   // 0/1
  int r = lane & 15, q = lane >> 4;
  int srow = t >> 2, schunk = t & 3;  // srow 0..31

  const unsigned short* Ag0 = W + (size_t)(M0 + srow)*Astride + schunk*8;
  const unsigned short* Ag1 = W + (size_t)(M0 + 32 + srow)*Astride + schunk*8;
  const unsigned short* Bg0 = X + (size_t)(T0 + srow)*Xstride + Xoff + schunk*8;
  const unsigned short* Bg1 = X + (size_t)(T0 + 32 + srow)*Xstride + Xoff + schunk*8;
  const unsigned short* Bg2 = X + (size_t)(T0 + 64 + srow)*Xstride + Xoff + schunk*8;
  const unsigned short* Bg3 = X + (size_t)(T0 + 96 + srow)*Xstride + Xoff + schunk*8;
  unsigned short* Aw0 = &As[srow*32 + schunk*8];
  unsigned short* Aw1 = &As[(32 + srow)*32 + schunk*8];
  unsigned short* Bw0 = &Bs[srow*32 + schunk*8];
  unsigned short* Bw1 = &Bs[(32 + srow)*32 + schunk*8];
  unsigned short* Bw2 = &Bs[(64 + srow)*32 + schunk*8];
  unsigned short* Bw3 = &Bs[(96 + srow)*32 + schunk*8];

  int Tw = wave*64;
  f32x4 acc[4][4];
  #pragma unroll
  for (int i=0;i<4;i++)
    #pragma unroll
    for (int j=0;j<4;j++)
      #pragma unroll
      for (int u=0;u<4;u++) acc[i][j][u] = 0.f;

  for (int k0=0; k0<K; k0+=32){
    short8 va0 = *(const short8*)(Ag0 + k0);
    short8 va1 = *(const short8*)(Ag1 + k0);
    short8 vb0 = *(const short8*)(Bg0 + k0);
    short8 vb1 = *(const short8*)(Bg1 + k0);
    short8 vb2 = *(const short8*)(Bg2 + k0);
    short8 vb3 = *(const short8*)(Bg3 + k0);
    if (k0) __syncthreads();
    *(short8*)Aw0 = va0; *(short8*)Aw1 = va1;
    *(short8*)Bw0 = vb0; *(short8*)Bw1 = vb1;
    *(short8*)Bw2 = vb2; *(short8*)Bw3 = vb3;
    __syncthreads();
    short8 a[4], bfr[4];
    #pragma unroll
    for (int i=0;i<4;i++) a[i]   = *(const short8*)(&As[(i*16 + r)*32 + q*8]);
    #pragma unroll
    for (int j=0;j<4;j++) bfr[j] = *(const short8*)(&Bs[(Tw + j*16 + r)*32 + q*8]);
    #pragma unroll
    for (int i=0;i<4;i++)
      #pragma unroll
      for (int j=0;j<4;j++)
        acc[i][j] = __builtin_amdgcn_mfma_f32_16x16x32_bf16(a[i], bfr[j], acc[i][j], 0, 0, 0);
  }
  gemm_epi<EPI,EXB>(acc, M0, T0+Tw, r, q, out, outStride, outOff,
                    sPtr, bPtr, extraIn, extraOffB, extraStride,
                    resOffB, resStride, resOff);
}

// ---------------- attention: 16 lanes/query, 8 ch/lane ----------------
// block 256 = 4 waves x 4 queries; grid 1024.
__global__ __launch_bounds__(256) void attn_kernel(
  unsigned qOff, unsigned kOff, unsigned vOff, unsigned idxOff,
  const float* __restrict__ in, const float* __restrict__ wpos,
  unsigned aggOff)
{
  const unsigned short* Q  = (const unsigned short*)(g_scratch + qOff);
  const unsigned short* Kf = (const unsigned short*)(g_scratch + kOff);
  const unsigned short* V  = (const unsigned short*)(g_scratch + vOff);
  const int* idx           = (const int*)(g_scratch + idxOff);
  unsigned short* agg      = (unsigned short*)(g_scratch + aggOff);

  int lane = threadIdx.x & 63, wv = threadIdx.x >> 6;
  int lg = lane >> 4;            // query-in-wave 0..3
  int cl = lane & 15;            // channel lane
  int t = blockIdx.x*16 + wv*4 + lg;
  int b = t >> 12, n = t & 4095;
  const float* xb = in + (size_t)b*9*NP;
  int c0 = cl*8;

  short8 qv = *(const short8*)(Q + (size_t)t*128 + c0);
  float qf[8];
  #pragma unroll
  for (int u=0;u<8;u++) qf[u] = bf2f((unsigned short)qv[u]);
  float xn = xb[n], yn = xb[NP+n], zn = xb[2*NP+n];
  float wp[8][3];
  #pragma unroll
  for (int u=0;u<8;u++){
    wp[u][0]=wpos[(c0+u)*3+0]; wp[u][1]=wpos[(c0+u)*3+1]; wp[u][2]=wpos[(c0+u)*3+2];
  }

  int mi[16]; float s[16];
  {
    int4 m0 = *(const int4*)(idx + (size_t)t*16 + 0);
    int4 m1 = *(const int4*)(idx + (size_t)t*16 + 4);
    int4 m2 = *(const int4*)(idx + (size_t)t*16 + 8);
    int4 m3 = *(const int4*)(idx + (size_t)t*16 + 12);
    mi[0]=m0.x&4095; mi[1]=m0.y&4095; mi[2]=m0.z&4095; mi[3]=m0.w&4095;
    mi[4]=m1.x&4095; mi[5]=m1.y&4095; mi[6]=m1.z&4095; mi[7]=m1.w&4095;
    mi[8]=m2.x&4095; mi[9]=m2.y&4095; mi[10]=m2.z&4095; mi[11]=m2.w&4095;
    mi[12]=m3.x&4095; mi[13]=m3.y&4095; mi[14]=m3.z&4095; mi[15]=m3.w&4095;
  }
  #pragma unroll
  for (int j=0;j<16;j++){
    short8 kv = *(const short8*)(Kf + ((size_t)(b<<12) + mi[j])*128 + c0);
    float p = 0.f;
    #pragma unroll
    for (int u=0;u<8;u++) p += qf[u]*bf2f((unsigned short)kv[u]);
    #pragma unroll
    for (int o=8;o>=1;o>>=1) p += __shfl_xor(p, o, 64);   // within 16-lane group
    s[j] = p;
  }
  const float scale = 0.08838834764831845f; // 1/sqrt(128)
  float mx = s[0];
  #pragma unroll
  for (int j=1;j<16;j++) mx = fmaxf(mx, s[j]);
  float e[16], sum = 0.f;
  #pragma unroll
  for (int j=0;j<16;j++){ e[j] = __expf((s[j]-mx)*scale); sum += e[j]; }
  float inv = 1.f / sum;

  float a[8];
  #pragma unroll
  for (int u=0;u<8;u++) a[u] = 0.f;
  #pragma unroll
  for (int j=0;j<16;j++){
    int m = mi[j];
    float w = e[j]*inv;
    short8 vvv = *(const short8*)(V + ((size_t)(b<<12) + m)*128 + c0);
    float rx = xn - xb[m];
    float ry = yn - xb[NP+m];
    float rz = zn - xb[2*NP+m];
    #pragma unroll
    for (int u=0;u<8;u++){
      float pos = wp[u][0]*rx + wp[u][1]*ry + wp[u][2]*rz;
      a[u] += w*(bf2f((unsigned short)vvv[u]) + pos);
    }
  }
  short8 st;
  #pragma unroll
  for (int u=0;u<8;u++) st[u] = (short)f2bf(a[u]);
  *(short8*)(agg + (size_t)t*128 + c0) = st;
}

// ---------------- max/mean pool over tokens (two-stage) ----------------
__global__ __launch_bounds__(256) void pool_part(unsigned xfOff, unsigned gpOff)
{
  const unsigned short* xf = (const unsigned short*)(g_scratch + xfOff);
  float* gp = (float*)(g_scratch + gpOff);   // [b][seg][2][1024]
  int b = blockIdx.x >> 7, cblk = (blockIdx.x >> 3) & 15, seg = blockIdx.x & 7;
  int cl = threadIdx.x & 63, tg = threadIdx.x >> 6;
  int c = cblk*64 + cl;
  float mx = -3.0e38f, sm = 0.f;
  for (int n = seg*512 + tg; n < (seg+1)*512; n += 4){
    float v = bf2f(xf[((size_t)(b<<12) + n)*1024 + c]);
    mx = fmaxf(mx, v); sm += v;
  }
  __shared__ float smx[4][64], ssm[4][64];
  smx[tg][cl]=mx; ssm[tg][cl]=sm;
  __syncthreads();
  if (tg==0){
    #pragma unroll
    for (int k=1;k<4;k++){ mx = fmaxf(mx, smx[k][cl]); sm += ssm[k][cl]; }
    gp[((b*8 + seg)*2 + 0)*1024 + c] = mx;
    gp[((b*8 + seg)*2 + 1)*1024 + c] = sm;
  }
}
__global__ __launch_bounds__(256) void pool_final(unsigned gpOff, unsigned gOff)
{
  const float* gp = (const float*)(g_scratch + gpOff);
  float* g = (float*)(g_scratch + gOff);
  int b = blockIdx.x;
  for (int c = threadIdx.x; c < 1024; c += 256){
    float mx = -3.0e38f, sm = 0.f;
    #pragma unroll
    for (int seg=0; seg<8; ++seg){
      mx = fmaxf(mx, gp[((b*8 + seg)*2 + 0)*1024 + c]);
      sm += gp[((b*8 + seg)*2 + 1)*1024 + c];
    }
    g[b*2048 + c] = mx;
    g[b*2048 + 1024 + c] = sm * (1.f/4096.f);
  }
}

// gb[b][o] = cls_bias1[o] + sum_c W1[o][1024+c]*g[b][c]
__global__ __launch_bounds__(256) void gterm_kernel(const float* __restrict__ w1,
                                                    const float* __restrict__ bias1,
                                                    unsigned gOff, unsigned gbOff)
{
  const float* g = (const float*)(g_scratch + gOff);
  float* gb = (float*)(g_scratch + gbOff);
  int b = blockIdx.x >> 3, og = (blockIdx.x & 7)*64;
  int ol = threadIdx.x & 63, cq = threadIdx.x >> 6;
  int o = og + ol;
  const float* wrow = w1 + (size_t)o*3072 + 1024 + cq*512;
  const float* gp = g + b*2048 + cq*512;
  float acc = 0.f;
  for (int c=0;c<512;c+=4){
    float4 wv4 = *(const float4*)(wrow + c);
    acc += wv4.x*gp[c] + wv4.y*gp[c+1] + wv4.z*gp[c+2] + wv4.w*gp[c+3];
  }
  __shared__ float sred[4][64];
  sred[cq][ol] = acc;
  __syncthreads();
  if (cq==0){
    acc += sred[1][ol] + sred[2][ol] + sred[3][ol];
    gb[b*512 + o] = acc + bias1[o];
  }
}

// ---------------- classifier head (O=13), fp32 out ----------------
__global__ __launch_bounds__(256) void cls3_kernel(unsigned c2Off,
                                                   const float* __restrict__ w3,
                                                   const float* __restrict__ bias3,
                                                   float* __restrict__ outp)
{
  const unsigned short* c2 = (const unsigned short*)(g_scratch + c2Off);
  __shared__ float wf[13*256];
  __shared__ float bf3[13];
  for (int i=threadIdx.x;i<13*256;i+=256) wf[i]=w3[i];
  if (threadIdx.x < 13) bf3[threadIdx.x]=bias3[threadIdx.x];
  __syncthreads();
  int lane = threadIdx.x & 63, wv = threadIdx.x >> 6;
  int tl = lane >> 2, cq = lane & 3;
  int t = blockIdx.x*64 + wv*16 + tl;
  const unsigned short* xrow = c2 + (size_t)t*256 + cq*64;
  float acc[13];
  #pragma unroll
  for (int o=0;o<13;o++) acc[o]=0.f;
  for (int c=0;c<64;c+=8){
    short8 xv = *(const short8*)(xrow + c);
    float xs[8];
    #pragma unroll
    for (int u=0;u<8;u++) xs[u]=bf2f((unsigned short)xv[u]);
    #pragma unroll
    for (int o=0;o<13;o++){
      const float* wr = wf + o*256 + cq*64 + c;
      #pragma unroll
      for (int u=0;u<8;u++) acc[o] += wr[u]*xs[u];
    }
  }
  #pragma unroll
  for (int o=0;o<13;o++){
    acc[o] += __shfl_xor(acc[o], 1, 64);
    acc[o] += __shfl_xor(acc[o], 2, 64);
  }
  if (cq==0){
    int b = t >> 12, n = t & 4095;
    #pragma unroll
    for (int o=0;o<13;o++)
      outp[((size_t)b*13 + o)*NP + n] = acc[o] + bf3[o];
  }
}

// ---------------- launch ----------------
extern "C" void kernel_launch(void* const* d_in, const int* in_sizes, int n_in,
                              void* d_out, int out_size, void* d_ws, size_t ws_size,
                              hipStream_t stream) {
  (void)in_sizes; (void)n_in; (void)out_size; (void)d_ws; (void)ws_size;
  const float* in      = (const float*)d_in[0];
  const float* emb_w1  = (const float*)d_in[1];
  const float* emb_s1  = (const float*)d_in[2];
  const float* emb_b1  = (const float*)d_in[3];
  const float* emb_w2  = (const float*)d_in[4];
  const float* emb_s2  = (const float*)d_in[5];
  const float* emb_b2  = (const float*)d_in[6];
  const float* blk_wq  = (const float*)d_in[7];
  const float* blk_wk  = (const float*)d_in[8];
  const float* blk_wv  = (const float*)d_in[9];
  const float* blk_wpos= (const float*)d_in[10];
  const float* blk_wo  = (const float*)d_in[11];
  const float* blk_s   = (const float*)d_in[12];
  const float* blk_b   = (const float*)d_in[13];
  const float* fuse_w  = (const float*)d_in[14];
  const float* fuse_s  = (const float*)d_in[15];
  const float* fuse_b  = (const float*)d_in[16];
  const float* cls_w1  = (const float*)d_in[17];
  const float* cls_b1  = (const float*)d_in[18];
  const float* cls_s1  = (const float*)d_in[19];
  const float* cls_sh1 = (const float*)d_in[20];
  const float* cls_w2  = (const float*)d_in[21];
  const float* cls_b2  = (const float*)d_in[22];
  const float* cls_s2  = (const float*)d_in[23];
  const float* cls_sh2 = (const float*)d_in[24];
  const float* cls_w3  = (const float*)d_in[25];
  const float* cls_b3  = (const float*)d_in[26];

  // byte offsets into g_scratch
  const unsigned MB = 1u<<20, KB = 1024u;
  const unsigned OFF_IDX   = 0;                 // 1 MB   int idx[T][16]
  const unsigned OFF_WQ    = 1*MB;              // 96 KB  bf16 (3,128,128)
  const unsigned OFF_WK    = 1*MB + 128*KB;     // 96 KB
  const unsigned OFF_WV    = 1*MB + 256*KB;     // 96 KB
  const unsigned OFF_WO    = 1*MB + 384*KB;     // 96 KB
  const unsigned OFF_WEMB2 = 1*MB + 512*KB;     // 32 KB  bf16 (128,128)
  const unsigned OFF_WFUSE = 1*MB + 576*KB;     // 768 KB bf16 (1024,384)
  const unsigned OFF_WW1   = 3*MB;              // 1 MB   bf16 (512,1024) x-half
  const unsigned OFF_WW2   = 4*MB;              // 256 KB bf16 (256,512)
  const unsigned OFF_X1    = 5*MB;              // 4 MB   bf16 (T,128)
  const unsigned OFF_X0    = 9*MB;              // 4 MB   bf16 (T,128)
  const unsigned OFF_XCAT  = 13*MB;             // 12 MB  bf16 (T,384)
  const unsigned OFF_QB    = 25*MB;             // 4 MB
  const unsigned OFF_KB    = 29*MB;             // 4 MB
  const unsigned OFF_VB    = 33*MB;             // 4 MB
  const unsigned OFF_AGG   = 37*MB;             // 4 MB
  const unsigned OFF_XF    = 41*MB;             // 32 MB  bf16 (T,1024)
  const unsigned OFF_C1    = 73*MB;             // 16 MB  bf16 (T,512)
  const unsigned OFF_C2    = 89*MB;             // 8 MB   bf16 (T,256)
  const unsigned OFF_G     = 97*MB;             // 32 KB  f32 (B,2048)
  const unsigned OFF_GB    = 97*MB + 64*KB;     // 8 KB   f32 (B,512)
  const unsigned OFF_GP    = 97*MB + 128*KB;    // 256 KB f32 pool partials
  const unsigned OFF_THR   = 97*MB + 512*KB;    // 64 KB  f32 thr[T]
  const unsigned OFF_PD    = 98*MB;             // 16 MB  f32 knn bound vals / p2 dists
  const unsigned OFF_PI    = 114*MB;            // 16 MB  int knn idx (p2)
  float* outp = (float*)d_out;                  // (B,13,N) f32

  // 0: fused weight conversion prepass (fp32 -> bf16 into scratch)
  CvtArgs ca;
  ca.src[0]=emb_w2;  ca.dstOff[0]=OFF_WEMB2; ca.n[0]=128*128;
  ca.src[1]=blk_wq;  ca.dstOff[1]=OFF_WQ;    ca.n[1]=3*128*128;
  ca.src[2]=blk_wk;  ca.dstOff[2]=OFF_WK;    ca.n[2]=3*128*128;
  ca.src[3]=blk_wv;  ca.dstOff[3]=OFF_WV;    ca.n[3]=3*128*128;
  ca.src[4]=blk_wo;  ca.dstOff[4]=OFF_WO;    ca.n[4]=3*128*128;
  ca.src[5]=fuse_w;  ca.dstOff[5]=OFF_WFUSE; ca.n[5]=1024*384;
  ca.src[6]=cls_w2;  ca.dstOff[6]=OFF_WW2;   ca.n[6]=256*512;
  ca.src[7]=cls_w1;  ca.dstOff[7]=OFF_WW1;   ca.n[7]=512*1024;
  cvt_all<<<dim3(64,8), 256, 0, stream>>>(ca);

  // 1-4: KNN (cheap-threshold two-pass)
  knn_p1<<<dim3(16,16,4), 256, 0, stream>>>(in, OFF_PD);
  knn_thr<<<dim3(64), 256, 0, stream>>>(OFF_PD, OFF_THR);
  knn_p2<<<dim3(16,16,4), 256, 0, stream>>>(in, OFF_THR, OFF_PD, OFF_PI);
  knn_mrg<<<dim3(64), 256, 0, stream>>>(OFF_PD, OFF_PI, OFF_IDX);
  // 5-6: embedding
  emb1_kernel<<<dim3(64,4), 256, 0, stream>>>(in, emb_w1, emb_s1, emb_b1, OFF_X1);
  gemm_small_lds<EPI_RELU_SB,false><<<dim3(2,128,1), 128, 0, stream>>>(
      OFF_WEMB2, OFF_WEMB2, OFF_WEMB2, OFF_X0, OFF_X0, OFF_X0,
      OFF_X1, 128, 0, 128, 0, emb_s2, emb_b2,
      nullptr, 0, 0, 0, 0, 0, 128, 128);
  // 7-9: transformer blocks
  for (int i=0;i<3;i++){
    unsigned wq = OFF_WQ + i*32768, wk = OFF_WK + i*32768;
    unsigned wv = OFF_WV + i*32768, wo = OFF_WO + i*32768;
    const float* wp = blk_wpos + i*128*3;
    const float* si = blk_s + i*128;
    const float* bi = blk_b + i*128;
    unsigned XiOff = (i==0) ? OFF_X0 : OFF_XCAT;
    int Xs = (i==0) ? 128 : 384;
    int Xo = (i==0) ? 0 : (i-1)*128;
    gemm_small_lds<EPI_PLAIN,false><<<dim3(2,128,3), 128, 0, stream>>>(
        wq, wk, wv, OFF_QB, OFF_KB, OFF_VB,
        XiOff, Xs, Xo, 128, 0, nullptr, nullptr,
        nullptr, 0, 0, 0, 0, 0, 128, 128);
    attn_kernel<<<dim3(1024), 256, 0, stream>>>(OFF_QB, OFF_KB, OFF_VB, OFF_IDX, in, wp, OFF_AGG);
    gemm_small_lds<EPI_RES,false><<<dim3(2,128,1), 128, 0, stream>>>(
        wo, wo, wo, OFF_XCAT, OFF_XCAT, OFF_XCAT,
        OFF_AGG, 128, 0, 384, i*128, si, bi,
        nullptr, 0, 0, XiOff, Xs, Xo, 128, 128);
  }
  // 10: fuse (leaky relu), LDS-staged + swizzled
  gemm_lds<EPI_LEAKY,false><<<dim3(8,128,1), 256, 0, stream>>>(
      OFF_WFUSE, OFF_WFUSE, OFF_WFUSE, OFF_XF, OFF_XF, OFF_XF,
      OFF_XCAT, 384, 0, 1024, 0, fuse_s, fuse_b,
      nullptr, 0, 0, 0, 0, 0, 384, 384);
  // 11-13: pooling (two-stage) + broadcast-g term of cls1 (fp32)
  pool_part<<<dim3(512), 256, 0, stream>>>(OFF_XF, OFF_GP);
  pool_final<<<dim3(4), 256, 0, stream>>>(OFF_GP, OFF_G);
  gterm_kernel<<<dim3(32), 256, 0, stream>>>(cls_w1, cls_b1, OFF_G, OFF_GB);
  // 14: cls1 (K=1024 x-half of W1; gb = W1[:,1024:]@g + bias1 as extra)
  gemm_lds<EPI_CLS,false><<<dim3(4,128,1), 256, 0, stream>>>(
      OFF_WW1, OFF_WW1, OFF_WW1, OFF_C1, OFF_C1, OFF_C1,
      OFF_XF, 1024, 0, 512, 0, cls_s1, cls_sh1,
      nullptr, OFF_GB, 512, 0, 0, 0, 1024, 1024);
  // 15: cls2 (K=512), LDS-staged
  gemm_lds<EPI_CLS,true><<<dim3(2,128,1), 256, 0, stream>>>(
      OFF_WW2, OFF_WW2, OFF_WW2, OFF_C2, OFF_C2, OFF_C2,
      OFF_C1, 512, 0, 256, 0, cls_s2, cls_sh2,
      cls_b2, 0, 0, 0, 0, 0, 512, 512);
  // 16: cls3 -> d_out (fp32)
  cls3_kernel<<<dim3(256), 256, 0, stream>>>(OFF_C2, cls_w3, cls_b3, outp);
}

// Round 16
// 509.624 us; speedup vs baseline: 1.0491x; 1.0491x over previous
//
#include <hip/hip_runtime.h>

// PVDST semseg, MI355X/gfx950. FP32 I/O. Round-16: un-regress knn_mrg.
//   - R15 post-mortem: mrg 64-block grid left 3/4 of CUs idle (occ 2.3%,
//     51us, latency-bound serial chunk walk). Revert to 256x64 grid AND
//     load each (query,chunk) dist+idx line as 4xfloat4 + 4xint4 up front
//     (8 independent 16B loads -> 1 latency round-trip per chunk), then
//     register-scan with sentinel break.
//   - p2 fma-prefilter + attn int4 idx loads kept (R15 wins).
// Rest identical to R15 (passed, absmax 1.95e-3).

#define NB 4
#define NP 4096
#define NT 16384   // NB*NP tokens

#define SCRATCH_BYTES (132u*1024u*1024u)
__device__ __align__(256) unsigned char g_scratch[SCRATCH_BYTES];

typedef __attribute__((ext_vector_type(8))) short short8;   // 8 x bf16 MFMA frag
typedef __attribute__((ext_vector_type(4))) float f32x4;    // MFMA acc
typedef __attribute__((ext_vector_type(4))) unsigned short ushort4v;

__device__ __forceinline__ float bf2f(unsigned short u){
  unsigned int v = ((unsigned int)u) << 16;
  return __builtin_bit_cast(float, v);
}
__device__ __forceinline__ unsigned short f2bf(float f){
  unsigned int x = __builtin_bit_cast(unsigned int, f);
  x += 0x7fffu + ((x >> 16) & 1u);     // RNE
  return (unsigned short)(x >> 16);
}
// numpy-matched: ((x*x)+(y*y))+(z*z), each op rounded (no fma contraction)
__device__ __forceinline__ float sq3(float x, float y, float z){
  return __fadd_rn(__fadd_rn(__fmul_rn(x,x), __fmul_rn(y,y)), __fmul_rn(z,z));
}

// sorted-4 insert: 7 native min/max, no masks
#define KINS4(a0,a1,a2,a3,dd) do{ float _d=(dd);\
  a3=fminf(fmaxf(a2,_d),a3); a2=fminf(fmaxf(a1,_d),a2);\
  a1=fminf(fmaxf(a0,_d),a1); a0=fminf(a0,_d);}while(0)

// dist-only sorted-ascending top-16 (thr kernel)
#define KDECLD float d0=3.0e38f,d1=3.0e38f,d2=3.0e38f,d3=3.0e38f,d4=3.0e38f,\
  d5=3.0e38f,d6=3.0e38f,d7=3.0e38f,d8=3.0e38f,d9=3.0e38f,d10=3.0e38f,\
  d11=3.0e38f,d12=3.0e38f,d13=3.0e38f,d14=3.0e38f,d15=3.0e38f
#define KINSD(dd) do{ float _d=(dd); \
  d15=fminf(fmaxf(d14,_d),d15); d14=fminf(fmaxf(d13,_d),d14); \
  d13=fminf(fmaxf(d12,_d),d13); d12=fminf(fmaxf(d11,_d),d12); \
  d11=fminf(fmaxf(d10,_d),d11); d10=fminf(fmaxf(d9 ,_d),d10); \
  d9 =fminf(fmaxf(d8 ,_d),d9 ); d8 =fminf(fmaxf(d7 ,_d),d8 ); \
  d7 =fminf(fmaxf(d6 ,_d),d7 ); d6 =fminf(fmaxf(d5 ,_d),d6 ); \
  d5 =fminf(fmaxf(d4 ,_d),d5 ); d4 =fminf(fmaxf(d3 ,_d),d4 ); \
  d3 =fminf(fmaxf(d2 ,_d),d3 ); d2 =fminf(fmaxf(d1 ,_d),d2 ); \
  d1 =fminf(fmaxf(d0 ,_d),d1 ); d0 =fminf(d0,_d); }while(0)

// full (dist,idx) stable insert (merge only; strict < => lower index wins)
#define KDECL KDECLD; int i0=0,i1=0,i2=0,i3=0,i4=0,i5=0,i6=0,i7=0,i8=0,\
  i9=0,i10=0,i11=0,i12=0,i13=0,i14=0,i15=0
#define KINS(dd,mm) do{ float _d=(dd); int _m=(mm); \
  bool c15 = _d < d15; \
  bool c14 = _d < d14;  i15 = c14 ? i14 : (c15 ? _m : i15);  d15 = fminf(fmaxf(d14,_d), d15); \
  bool c13 = _d < d13;  i14 = c13 ? i13 : (c14 ? _m : i14);  d14 = fminf(fmaxf(d13,_d), d14); \
  bool c12 = _d < d12;  i13 = c12 ? i12 : (c13 ? _m : i13);  d13 = fminf(fmaxf(d12,_d), d13); \
  bool c11 = _d < d11;  i12 = c11 ? i11 : (c12 ? _m : i12);  d12 = fminf(fmaxf(d11,_d), d12); \
  bool c10 = _d < d10;  i11 = c10 ? i10 : (c11 ? _m : i11);  d11 = fminf(fmaxf(d10,_d), d11); \
  bool c9  = _d < d9;   i10 = c9  ? i9  : (c10 ? _m : i10);  d10 = fminf(fmaxf(d9 ,_d), d10); \
  bool c8  = _d < d8;   i9  = c8  ? i8  : (c9  ? _m : i9 );  d9  = fminf(fmaxf(d8 ,_d), d9 ); \
  bool c7  = _d < d7;   i8  = c7  ? i7  : (c8  ? _m : i8 );  d8  = fminf(fmaxf(d7 ,_d), d8 ); \
  bool c6  = _d < d6;   i7  = c6  ? i6  : (c7  ? _m : i7 );  d7  = fminf(fmaxf(d6 ,_d), d7 ); \
  bool c5  = _d < d5;   i6  = c5  ? i5  : (c6  ? _m : i6 );  d6  = fminf(fmaxf(d5 ,_d), d6 ); \
  bool c4  = _d < d4;   i5  = c4  ? i4  : (c5  ? _m : i5 );  d5  = fminf(fmaxf(d4 ,_d), d5 ); \
  bool c3  = _d < d3;   i4  = c3  ? i3  : (c4  ? _m : i4 );  d4  = fminf(fmaxf(d3 ,_d), d4 ); \
  bool c2  = _d < d2;   i3  = c2  ? i2  : (c3  ? _m : i3 );  d3  = fminf(fmaxf(d2 ,_d), d3 ); \
  bool c1  = _d < d1;   i2  = c1  ? i1  : (c2  ? _m : i2 );  d2  = fminf(fmaxf(d1 ,_d), d2 ); \
  bool c0  = _d < d0;   i1  = c0  ? i0  : (c1  ? _m : i1 );  d1  = fminf(fmaxf(d0 ,_d), d1 ); \
  i0 = c0 ? _m : i0;  d0 = fminf(d0,_d); }while(0)

// ---------------- fused weight fp32 -> bf16 conversion prepass ----------------
struct CvtArgs {
  const float* src[8];
  unsigned dstOff[8];
  int n[8];
};
__global__ __launch_bounds__(256) void cvt_all(CvtArgs a)
{
  int y = blockIdx.y;
  const float* src = a.src[y];
  unsigned short* dst = (unsigned short*)(g_scratch + a.dstOff[y]);
  int n = a.n[y];
  if (y == 7){
    for (int i = blockIdx.x*256 + threadIdx.x; i < n; i += gridDim.x*256){
      int r = i >> 10, c = i & 1023;
      dst[i] = f2bf(src[(size_t)r*3072 + c]);
    }
  } else {
    for (int i = blockIdx.x*256 + threadIdx.x; i < n; i += gridDim.x*256)
      dst[i] = f2bf(src[i]);
  }
}

// ---------------- KNN pass1: 4x sorted-4 bound lists, fma dist ----------------
__global__ __launch_bounds__(256) void knn_p1(const float* __restrict__ in,
                                              unsigned pdOff)
{
  float* pdist = (float*)(g_scratch + pdOff);
  __shared__ float4 sp[256];
  int b = blockIdx.z, qc = blockIdx.x, cc = blockIdx.y;
  const float* xb = in + (size_t)b*9*NP;
  int base = cc*256;
  {
    int i = threadIdx.x;
    float x = xb[base+i], y = xb[NP+base+i], z = xb[2*NP+base+i];
    sp[i] = make_float4(x,y,z, x*x+y*y+z*z);
  }
  __syncthreads();
  int n = qc*256 + threadIdx.x;
  float xn=xb[n], yn=xb[NP+n], zn=xb[2*NP+n];
  float sqn = xn*xn + yn*yn + zn*zn;
  float A0=3e38f,A1=3e38f,A2=3e38f,A3=3e38f;
  float B0=3e38f,B1=3e38f,B2=3e38f,B3=3e38f;
  float C0=3e38f,C1=3e38f,C2=3e38f,C3=3e38f;
  float D0=3e38f,D1=3e38f,D2=3e38f,D3=3e38f;
  for (int mm=0; mm<256; mm+=4){
    float4 p0 = sp[mm], p1 = sp[mm+1], p2 = sp[mm+2], p3 = sp[mm+3];
    float e0 = sqn + p0.w - 2.f*(xn*p0.x + yn*p0.y + zn*p0.z);
    float e1 = sqn + p1.w - 2.f*(xn*p1.x + yn*p1.y + zn*p1.z);
    float e2 = sqn + p2.w - 2.f*(xn*p2.x + yn*p2.y + zn*p2.z);
    float e3 = sqn + p3.w - 2.f*(xn*p3.x + yn*p3.y + zn*p3.z);
    KINS4(A0,A1,A2,A3,e0);
    KINS4(B0,B1,B2,B3,e1);
    KINS4(C0,C1,C2,C3,e2);
    KINS4(D0,D1,D2,D3,e3);
  }
  size_t ob = ((size_t)(b*16+cc)*16)*NP + n;
  pdist[ob+ 0*(size_t)NP]=A0; pdist[ob+ 1*(size_t)NP]=A1; pdist[ob+ 2*(size_t)NP]=A2; pdist[ob+ 3*(size_t)NP]=A3;
  pdist[ob+ 4*(size_t)NP]=B0; pdist[ob+ 5*(size_t)NP]=B1; pdist[ob+ 6*(size_t)NP]=B2; pdist[ob+ 7*(size_t)NP]=B3;
  pdist[ob+ 8*(size_t)NP]=C0; pdist[ob+ 9*(size_t)NP]=C1; pdist[ob+10*(size_t)NP]=C2; pdist[ob+11*(size_t)NP]=C3;
  pdist[ob+12*(size_t)NP]=D0; pdist[ob+13*(size_t)NP]=D1; pdist[ob+14*(size_t)NP]=D2; pdist[ob+15*(size_t)NP]=D3;
}

// ---------------- KNN thr: 16th-smallest of the 256 bound values + margin ----
__global__ __launch_bounds__(256) void knn_thr(unsigned pdOff, unsigned thrOff)
{
  const float* pdist = (const float*)(g_scratch + pdOff);
  float* thr = (float*)(g_scratch + thrOff);
  int t = blockIdx.x*256 + threadIdx.x;
  int b = t >> 12, n = t & 4095;
  KDECLD;
  for (int cc=0; cc<16; ++cc){
    size_t ob = ((size_t)(b*16+cc)*16)*NP + n;
    #pragma unroll
    for (int j=0;j<16;j++){ KINSD(pdist[ob + (size_t)j*NP]); }
  }
  thr[t] = d15*1.000002f + 2e-4f;   // margin >> fma-vs-_rn error
}

// ---------------- KNN pass2: fma prefilter + exact _rn qualify --------
__global__ __launch_bounds__(256) void knn_p2(const float* __restrict__ in,
                                              unsigned thrOff, unsigned pdOff, unsigned piOff)
{
  const float* thr = (const float*)(g_scratch + thrOff);
  float* pdist = (float*)(g_scratch + pdOff);
  int*   pidx  = (int*)  (g_scratch + piOff);
  __shared__ float4 sp[256];
  int b = blockIdx.z, qc = blockIdx.x, cc = blockIdx.y;
  const float* xb = in + (size_t)b*9*NP;
  int base = cc*256;
  {
    int i = threadIdx.x;
    float x = xb[base+i], y = xb[NP+base+i], z = xb[2*NP+base+i];
    sp[i] = make_float4(x,y,z,sq3(x,y,z));
  }
  __syncthreads();
  int n = qc*256 + threadIdx.x;
  float xn=xb[n], yn=xb[NP+n], zn=xb[2*NP+n];
  float sqn = sq3(xn,yn,zn);
  float th = thr[(b<<12) + n];
  float thx = th*1.000001f + 1e-3f;   // prefilter slack >= |d_fma - d_rn|
  size_t o = ((size_t)((b*16 + cc)*NP + n))*16;
  int cnt = 0;
  for (int mm=0; mm<256; ++mm){
    float4 p = sp[mm];
    float dfma = sqn + p.w - 2.f*(xn*p.x + yn*p.y + zn*p.z);  // contracted
    if (dfma <= thx && cnt < 16){
      // exact numpy-rounded distance; original qualifying test preserved
      float dot = __fadd_rn(__fadd_rn(__fmul_rn(xn,p.x), __fmul_rn(yn,p.y)), __fmul_rn(zn,p.z));
      float d = __fsub_rn(__fadd_rn(sqn, p.w), __fmul_rn(2.0f, dot));
      if (d <= th){
        pdist[o+cnt] = d;
        pidx[o+cnt] = base + mm;
        cnt++;
      }
    }
  }
  if (cnt < 16) pdist[o+cnt] = 3.0e38f;   // sentinel terminator
}

// ---------------- KNN final merge (vectorized line loads) ----------------
// grid 256 x 64 (all CUs). Per chunk: 4xfloat4 + 4xint4 up front (one 64B
// line each, 8 independent loads), then register scan with sentinel break.
__global__ __launch_bounds__(64) void knn_mrg(unsigned pdOff, unsigned piOff, unsigned idxOff)
{
  const float* pdist = (const float*)(g_scratch + pdOff);
  const int*   pidx  = (const int*)  (g_scratch + piOff);
  int*         idxOut= (int*)(g_scratch + idxOff);
  int t = blockIdx.x*64 + threadIdx.x;
  int b = t >> 12, n = t & 4095;
  KDECL;
  for (int cc=0; cc<16; ++cc){
    size_t o = ((size_t)((b*16 + cc)*NP + n))*16;
    float4 pdv0 = *(const float4*)(pdist + o);
    float4 pdv1 = *(const float4*)(pdist + o + 4);
    float4 pdv2 = *(const float4*)(pdist + o + 8);
    float4 pdv3 = *(const float4*)(pdist + o + 12);
    int4   piv0 = *(const int4*)(pidx + o);
    int4   piv1 = *(const int4*)(pidx + o + 4);
    int4   piv2 = *(const int4*)(pidx + o + 8);
    int4   piv3 = *(const int4*)(pidx + o + 12);
    float pdv[16] = {pdv0.x,pdv0.y,pdv0.z,pdv0.w, pdv1.x,pdv1.y,pdv1.z,pdv1.w,
                     pdv2.x,pdv2.y,pdv2.z,pdv2.w, pdv3.x,pdv3.y,pdv3.z,pdv3.w};
    int   piv[16] = {piv0.x,piv0.y,piv0.z,piv0.w, piv1.x,piv1.y,piv1.z,piv1.w,
                     piv2.x,piv2.y,piv2.z,piv2.w, piv3.x,piv3.y,piv3.z,piv3.w};
    #pragma unroll 1
    for (int j=0;j<16;j++){
      float pd = pdv[j];
      if (pd >= 1.0e38f) break;          // sentinel
      KINS(pd, piv[j]);
    }
  }
  idxOut[t*16+ 0]=i0;  idxOut[t*16+ 1]=i1;  idxOut[t*16+ 2]=i2;  idxOut[t*16+ 3]=i3;
  idxOut[t*16+ 4]=i4;  idxOut[t*16+ 5]=i5;  idxOut[t*16+ 6]=i6;  idxOut[t*16+ 7]=i7;
  idxOut[t*16+ 8]=i8;  idxOut[t*16+ 9]=i9;  idxOut[t*16+10]=i10; idxOut[t*16+11]=i11;
  idxOut[t*16+12]=i12; idxOut[t*16+13]=i13; idxOut[t*16+14]=i14; idxOut[t*16+15]=i15;
}

// ---------------- embedding conv1 (Cin=9), output-split ----------------
__global__ __launch_bounds__(256) void emb1_kernel(const float* __restrict__ in,
                                                   const float* __restrict__ w1,
                                                   const float* __restrict__ s1,
                                                   const float* __restrict__ b1,
                                                   unsigned x1Off)
{
  unsigned short* x1 = (unsigned short*)(g_scratch + x1Off);
  int og = blockIdx.y*32;
  __shared__ float wf[32*9], sf[32], bf_[32];
  for (int i = threadIdx.x; i < 32*9; i += 256) wf[i] = w1[og*9 + i];
  if (threadIdx.x < 32){ sf[threadIdx.x]=s1[og+threadIdx.x]; bf_[threadIdx.x]=b1[og+threadIdx.x]; }
  __syncthreads();
  int t = blockIdx.x*256 + threadIdx.x;
  int b = t >> 12, n = t & 4095;
  float v[9];
  #pragma unroll
  for (int c=0;c<9;c++) v[c] = in[((size_t)b*9 + c)*NP + n];
  for (int o=0;o<32;o+=2){
    float a0=0.f, a1=0.f;
    #pragma unroll
    for (int c=0;c<9;c++){ a0 += wf[o*9+c]*v[c]; a1 += wf[(o+1)*9+c]*v[c]; }
    a0 = fmaxf(sf[o]*a0 + bf_[o], 0.f);
    a1 = fmaxf(sf[o+1]*a1 + bf_[o+1], 0.f);
    unsigned pk = (unsigned)f2bf(a0) | ((unsigned)f2bf(a1) << 16);
    *(unsigned*)(x1 + (size_t)t*128 + og + o) = pk;
  }
}

// ---------------- GEMM epilogue (shared) ----------------
enum { EPI_PLAIN=0, EPI_RELU_SB=1, EPI_RES=2, EPI_LEAKY=3, EPI_CLS=4 };

template<int EPI, bool EXB>
__device__ __forceinline__ void gemm_epi(
    f32x4 (&acc)[4][4], int M0, int T0, int r, int q,
    unsigned short* out, int outStride, int outOff,
    const float* sPtr, const float* bPtr,
    const float* extraIn, unsigned extraOffB, int extraStride,
    unsigned resOffB, int resStride, int resOff)
{
  #pragma unroll
  for (int i=0;i<4;i++){
    int m = M0 + i*16 + q*4;
    float sv[4], bv[4];
    if constexpr (EPI != EPI_PLAIN){
      #pragma unroll
      for (int u=0;u<4;u++){ sv[u]=sPtr[m+u]; bv[u]=bPtr[m+u]; }
    }
    #pragma unroll
    for (int j=0;j<4;j++){
      int token = T0 + j*16 + r;
      float ex[4];
      if constexpr (EPI == EPI_CLS){
        int bb = token >> 12;
        #pragma unroll
        for (int u=0;u<4;u++)
          ex[u] = EXB ? extraIn[bb*extraStride + m + u]
                      : ((const float*)(g_scratch + extraOffB))[bb*extraStride + m + u];
      }
      float resv[4];
      if constexpr (EPI == EPI_RES){
        const unsigned short* resPtr = (const unsigned short*)(g_scratch + resOffB);
        ushort4v rv = *(const ushort4v*)(resPtr + (size_t)token*resStride + resOff + m);
        #pragma unroll
        for (int u=0;u<4;u++) resv[u]=bf2f(rv[u]);
      }
      ushort4v ov;
      #pragma unroll
      for (int u=0;u<4;u++){
        float aa = acc[i][j][u];
        float vo;
        if constexpr (EPI == EPI_PLAIN)        vo = aa;
        else if constexpr (EPI == EPI_RELU_SB) vo = fmaxf(sv[u]*aa + bv[u], 0.f);
        else if constexpr (EPI == EPI_RES)     vo = resv[u] + fmaxf(sv[u]*aa + bv[u], 0.f);
        else if constexpr (EPI == EPI_LEAKY){  float tt = sv[u]*aa + bv[u]; vo = tt>0.f ? tt : 0.2f*tt; }
        else { vo = fmaxf(sv[u]*(aa + ex[u]) + bv[u], 0.f); }
        ov[u] = f2bf(vo);
      }
      *(ushort4v*)(out + (size_t)token*outStride + outOff + m) = ov;
    }
  }
}

// ---------------- LDS-staged GEMM: 128Mx128T, BK=32 (fuse, cls1, cls2) -------
template<int EPI, bool EXB>
__global__ __launch_bounds__(256) void gemm_lds(
    unsigned W0off, unsigned W1off, unsigned W2off,
    unsigned O0off, unsigned O1off, unsigned O2off,
    unsigned XoffB, int Xstride, int Xoff,
    int outStride, int outOff,
    const float* sPtr, const float* bPtr,
    const float* extraIn, unsigned extraOffB, int extraStride,
    unsigned resOffB, int resStride, int resOff,
    int K, int Astride)
{
  __shared__ unsigned short As[128*32];
  __shared__ unsigned short Bs[128*32];
  const unsigned short* X = (const unsigned short*)(g_scratch + XoffB);
  unsigned wOffB   = (blockIdx.z==0) ? W0off : ((blockIdx.z==1) ? W1off : W2off);
  unsigned outOffB = (blockIdx.z==0) ? O0off : ((blockIdx.z==1) ? O1off : O2off);
  const unsigned short* W = (const unsigned short*)(g_scratch + wOffB);
  unsigned short* out = (unsigned short*)(g_scratch + outOffB);
  int lin = blockIdx.x + gridDim.x*blockIdx.y;
  int bx = lin >> 7;
  int by = (lin & 7)*16 + ((lin >> 3) & 15);
  int M0 = bx*128, T0 = by*128;
  int t = threadIdx.x;
  int lane = t & 63, wave = t >> 6;
  int r = lane & 15, q = lane >> 4;
  int srow = t >> 2, schunk = t & 3;

  const unsigned short* Ag0 = W + (size_t)(M0 + srow)*Astride + schunk*8;
  const unsigned short* Ag1 = W + (size_t)(M0 + 64 + srow)*Astride + schunk*8;
  const unsigned short* Bg0 = X + (size_t)(T0 + srow)*Xstride + Xoff + schunk*8;
  const unsigned short* Bg1 = X + (size_t)(T0 + 64 + srow)*Xstride + Xoff + schunk*8;
  unsigned short* Aw0 = &As[srow*32 + schunk*8];
  unsigned short* Aw1 = &As[(64 + srow)*32 + schunk*8];
  unsigned short* Bw0 = &Bs[srow*32 + schunk*8];
  unsigned short* Bw1 = &Bs[(64 + srow)*32 + schunk*8];

  int Mw = (wave>>1)*64, Tw = (wave&1)*64;
  f32x4 acc[4][4];
  #pragma unroll
  for (int i=0;i<4;i++)
    #pragma unroll
    for (int j=0;j<4;j++)
      #pragma unroll
      for (int u=0;u<4;u++) acc[i][j][u] = 0.f;

  for (int k0=0; k0<K; k0+=32){
    short8 va0 = *(const short8*)(Ag0 + k0);
    short8 va1 = *(const short8*)(Ag1 + k0);
    short8 vb0 = *(const short8*)(Bg0 + k0);
    short8 vb1 = *(const short8*)(Bg1 + k0);
    if (k0) __syncthreads();
    *(short8*)Aw0 = va0; *(short8*)Aw1 = va1;
    *(short8*)Bw0 = vb0; *(short8*)Bw1 = vb1;
    __syncthreads();
    short8 a[4], bfr[4];
    #pragma unroll
    for (int i=0;i<4;i++) a[i]   = *(const short8*)(&As[(Mw + i*16 + r)*32 + q*8]);
    #pragma unroll
    for (int j=0;j<4;j++) bfr[j] = *(const short8*)(&Bs[(Tw + j*16 + r)*32 + q*8]);
    #pragma unroll
    for (int i=0;i<4;i++)
      #pragma unroll
      for (int j=0;j<4;j++)
        acc[i][j] = __builtin_amdgcn_mfma_f32_16x16x32_bf16(a[i], bfr[j], acc[i][j], 0, 0, 0);
  }
  gemm_epi<EPI,EXB>(acc, M0+Mw, T0+Tw, r, q, out, outStride, outOff,
                    sPtr, bPtr, extraIn, extraOffB, extraStride,
                    resOffB, resStride, resOff);
}

// ---------------- LDS-staged 2-wave 64Mx128T (K=128 sites: emb2, qkv, wo) ----
template<int EPI, bool EXB>
__global__ __launch_bounds__(128) void gemm_small_lds(
    unsigned W0off, unsigned W1off, unsigned W2off,
    unsigned O0off, unsigned O1off, unsigned O2off,
    unsigned XoffB, int Xstride, int Xoff,
    int outStride, int outOff,
    const float* sPtr, const float* bPtr,
    const float* extraIn, unsigned extraOffB, int extraStride,
    unsigned resOffB, int resStride, int resOff,
    int K, int Astride)
{
  __shared__ unsigned short As[64*32];    // 4 KB
  __shared__ unsigned short Bs[128*32];   // 8 KB
  const unsigned short* X = (const unsigned short*)(g_scratch + XoffB);
  unsigned wOffB   = (blockIdx.z==0) ? W0off : ((blockIdx.z==1) ? W1off : W2off);
  unsigned outOffB = (blockIdx.z==0) ? O0off : ((blockIdx.z==1) ? O1off : O2off);
  const unsigned short* W = (const unsigned short*)(g_scratch + wOffB);
  unsigned short* out = (unsigned short*)(g_scratch + outOffB);
  int M0 = blockIdx.x*64, T0 = blockIdx.y*128;
  int t = threadIdx.x;
  int lane = t & 63, wave = t >> 6;   // 0/1
  int r = lane & 15, q = lane >> 4;
  int srow = t >> 2, schunk = t & 3;  // srow 0..31

  const unsigned short* Ag0 = W + (size_t)(M0 + srow)*Astride + schunk*8;
  const unsigned short* Ag1 = W + (size_t)(M0 + 32 + srow)*Astride + schunk*8;
  const unsigned short* Bg0 = X + (size_t)(T0 + srow)*Xstride + Xoff + schunk*8;
  const unsigned short* Bg1 = X + (size_t)(T0 + 32 + srow)*Xstride + Xoff + schunk*8;
  const unsigned short* Bg2 = X + (size_t)(T0 + 64 + srow)*Xstride + Xoff + schunk*8;
  const unsigned short* Bg3 = X + (size_t)(T0 + 96 + srow)*Xstride + Xoff + schunk*8;
  unsigned short* Aw0 = &As[srow*32 + schunk*8];
  unsigned short* Aw1 = &As[(32 + srow)*32 + schunk*8];
  unsigned short* Bw0 = &Bs[srow*32 + schunk*8];
  unsigned short* Bw1 = &Bs[(32 + srow)*32 + schunk*8];
  unsigned short* Bw2 = &Bs[(64 + srow)*32 + schunk*8];
  unsigned short* Bw3 = &Bs[(96 + srow)*32 + schunk*8];

  int Tw = wave*64;
  f32x4 acc[4][4];
  #pragma unroll
  for (int i=0;i<4;i++)
    #pragma unroll
    for (int j=0;j<4;j++)
      #pragma unroll
      for (int u=0;u<4;u++) acc[i][j][u] = 0.f;

  for (int k0=0; k0<K; k0+=32){
    short8 va0 = *(const short8*)(Ag0 + k0);
    short8 va1 = *(const short8*)(Ag1 + k0);
    short8 vb0 = *(const short8*)(Bg0 + k0);
    short8 vb1 = *(const short8*)(Bg1 + k0);
    short8 vb2 = *(const short8*)(Bg2 + k0);
    short8 vb3 = *(const short8*)(Bg3 + k0);
    if (k0) __syncthreads();
    *(short8*)Aw0 = va0; *(short8*)Aw1 = va1;
    *(short8*)Bw0 = vb0; *(short8*)Bw1 = vb1;
    *(short8*)Bw2 = vb2; *(short8*)Bw3 = vb3;
    __syncthreads();
    short8 a[4], bfr[4];
    #pragma unroll
    for (int i=0;i<4;i++) a[i]   = *(const short8*)(&As[(i*16 + r)*32 + q*8]);
    #pragma unroll
    for (int j=0;j<4;j++) bfr[j] = *(const short8*)(&Bs[(Tw + j*16 + r)*32 + q*8]);
    #pragma unroll
    for (int i=0;i<4;i++)
      #pragma unroll
      for (int j=0;j<4;j++)
        acc[i][j] = __builtin_amdgcn_mfma_f32_16x16x32_bf16(a[i], bfr[j], acc[i][j], 0, 0, 0);
  }
  gemm_epi<EPI,EXB>(acc, M0, T0+Tw, r, q, out, outStride, outOff,
                    sPtr, bPtr, extraIn, extraOffB, extraStride,
                    resOffB, resStride, resOff);
}

// ---------------- attention: 16 lanes/query, 8 ch/lane ----------------
// block 256 = 4 waves x 4 queries; grid 1024.
__global__ __launch_bounds__(256) void attn_kernel(
  unsigned qOff, unsigned kOff, unsigned vOff, unsigned idxOff,
  const float* __restrict__ in, const float* __restrict__ wpos,
  unsigned aggOff)
{
  const unsigned short* Q  = (const unsigned short*)(g_scratch + qOff);
  const unsigned short* Kf = (const unsigned short*)(g_scratch + kOff);
  const unsigned short* V  = (const unsigned short*)(g_scratch + vOff);
  const int* idx           = (const int*)(g_scratch + idxOff);
  unsigned short* agg      = (unsigned short*)(g_scratch + aggOff);

  int lane = threadIdx.x & 63, wv = threadIdx.x >> 6;
  int lg = lane >> 4;            // query-in-wave 0..3
  int cl = lane & 15;            // channel lane
  int t = blockIdx.x*16 + wv*4 + lg;
  int b = t >> 12, n = t & 4095;
  const float* xb = in + (size_t)b*9*NP;
  int c0 = cl*8;

  short8 qv = *(const short8*)(Q + (size_t)t*128 + c0);
  float qf[8];
  #pragma unroll
  for (int u=0;u<8;u++) qf[u] = bf2f((unsigned short)qv[u]);
  float xn = xb[n], yn = xb[NP+n], zn = xb[2*NP+n];
  float wp[8][3];
  #pragma unroll
  for (int u=0;u<8;u++){
    wp[u][0]=wpos[(c0+u)*3+0]; wp[u][1]=wpos[(c0+u)*3+1]; wp[u][2]=wpos[(c0+u)*3+2];
  }

  int mi[16]; float s[16];
  {
    int4 m0 = *(const int4*)(idx + (size_t)t*16 + 0);
    int4 m1 = *(const int4*)(idx + (size_t)t*16 + 4);
    int4 m2 = *(const int4*)(idx + (size_t)t*16 + 8);
    int4 m3 = *(const int4*)(idx + (size_t)t*16 + 12);
    mi[0]=m0.x&4095; mi[1]=m0.y&4095; mi[2]=m0.z&4095; mi[3]=m0.w&4095;
    mi[4]=m1.x&4095; mi[5]=m1.y&4095; mi[6]=m1.z&4095; mi[7]=m1.w&4095;
    mi[8]=m2.x&4095; mi[9]=m2.y&4095; mi[10]=m2.z&4095; mi[11]=m2.w&4095;
    mi[12]=m3.x&4095; mi[13]=m3.y&4095; mi[14]=m3.z&4095; mi[15]=m3.w&4095;
  }
  #pragma unroll
  for (int j=0;j<16;j++){
    short8 kv = *(const short8*)(Kf + ((size_t)(b<<12) + mi[j])*128 + c0);
    float p = 0.f;
    #pragma unroll
    for (int u=0;u<8;u++) p += qf[u]*bf2f((unsigned short)kv[u]);
    #pragma unroll
    for (int o=8;o>=1;o>>=1) p += __shfl_xor(p, o, 64);   // within 16-lane group
    s[j] = p;
  }
  const float scale = 0.08838834764831845f; // 1/sqrt(128)
  float mx = s[0];
  #pragma unroll
  for (int j=1;j<16;j++) mx = fmaxf(mx, s[j]);
  float e[16], sum = 0.f;
  #pragma unroll
  for (int j=0;j<16;j++){ e[j] = __expf((s[j]-mx)*scale); sum += e[j]; }
  float inv = 1.f / sum;

  float a[8];
  #pragma unroll
  for (int u=0;u<8;u++) a[u] = 0.f;
  #pragma unroll
  for (int j=0;j<16;j++){
    int m = mi[j];
    float w = e[j]*inv;
    short8 vvv = *(const short8*)(V + ((size_t)(b<<12) + m)*128 + c0);
    float rx = xn - xb[m];
    float ry = yn - xb[NP+m];
    float rz = zn - xb[2*NP+m];
    #pragma unroll
    for (int u=0;u<8;u++){
      float pos = wp[u][0]*rx + wp[u][1]*ry + wp[u][2]*rz;
      a[u] += w*(bf2f((unsigned short)vvv[u]) + pos);
    }
  }
  short8 st;
  #pragma unroll
  for (int u=0;u<8;u++) st[u] = (short)f2bf(a[u]);
  *(short8*)(agg + (size_t)t*128 + c0) = st;
}

// ---------------- max/mean pool over tokens (two-stage) ----------------
__global__ __launch_bounds__(256) void pool_part(unsigned xfOff, unsigned gpOff)
{
  const unsigned short* xf = (const unsigned short*)(g_scratch + xfOff);
  float* gp = (float*)(g_scratch + gpOff);   // [b][seg][2][1024]
  int b = blockIdx.x >> 7, cblk = (blockIdx.x >> 3) & 15, seg = blockIdx.x & 7;
  int cl = threadIdx.x & 63, tg = threadIdx.x >> 6;
  int c = cblk*64 + cl;
  float mx = -3.0e38f, sm = 0.f;
  for (int n = seg*512 + tg; n < (seg+1)*512; n += 4){
    float v = bf2f(xf[((size_t)(b<<12) + n)*1024 + c]);
    mx = fmaxf(mx, v); sm += v;
  }
  __shared__ float smx[4][64], ssm[4][64];
  smx[tg][cl]=mx; ssm[tg][cl]=sm;
  __syncthreads();
  if (tg==0){
    #pragma unroll
    for (int k=1;k<4;k++){ mx = fmaxf(mx, smx[k][cl]); sm += ssm[k][cl]; }
    gp[((b*8 + seg)*2 + 0)*1024 + c] = mx;
    gp[((b*8 + seg)*2 + 1)*1024 + c] = sm;
  }
}
__global__ __launch_bounds__(256) void pool_final(unsigned gpOff, unsigned gOff)
{
  const float* gp = (const float*)(g_scratch + gpOff);
  float* g = (float*)(g_scratch + gOff);
  int b = blockIdx.x;
  for (int c = threadIdx.x; c < 1024; c += 256){
    float mx = -3.0e38f, sm = 0.f;
    #pragma unroll
    for (int seg=0; seg<8; ++seg){
      mx = fmaxf(mx, gp[((b*8 + seg)*2 + 0)*1024 + c]);
      sm += gp[((b*8 + seg)*2 + 1)*1024 + c];
    }
    g[b*2048 + c] = mx;
    g[b*2048 + 1024 + c] = sm * (1.f/4096.f);
  }
}

// gb[b][o] = cls_bias1[o] + sum_c W1[o][1024+c]*g[b][c]
__global__ __launch_bounds__(256) void gterm_kernel(const float* __restrict__ w1,
                                                    const float* __restrict__ bias1,
                                                    unsigned gOff, unsigned gbOff)
{
  const float* g = (const float*)(g_scratch + gOff);
  float* gb = (float*)(g_scratch + gbOff);
  int b = blockIdx.x >> 3, og = (blockIdx.x & 7)*64;
  int ol = threadIdx.x & 63, cq = threadIdx.x >> 6;
  int o = og + ol;
  const float* wrow = w1 + (size_t)o*3072 + 1024 + cq*512;
  const float* gp = g + b*2048 + cq*512;
  float acc = 0.f;
  for (int c=0;c<512;c+=4){
    float4 wv4 = *(const float4*)(wrow + c);
    acc += wv4.x*gp[c] + wv4.y*gp[c+1] + wv4.z*gp[c+2] + wv4.w*gp[c+3];
  }
  __shared__ float sred[4][64];
  sred[cq][ol] = acc;
  __syncthreads();
  if (cq==0){
    acc += sred[1][ol] + sred[2][ol] + sred[3][ol];
    gb[b*512 + o] = acc + bias1[o];
  }
}

// ---------------- classifier head (O=13), fp32 out ----------------
__global__ __launch_bounds__(256) void cls3_kernel(unsigned c2Off,
                                                   const float* __restrict__ w3,
                                                   const float* __restrict__ bias3,
                                                   float* __restrict__ outp)
{
  const unsigned short* c2 = (const unsigned short*)(g_scratch + c2Off);
  __shared__ float wf[13*256];
  __shared__ float bf3[13];
  for (int i=threadIdx.x;i<13*256;i+=256) wf[i]=w3[i];
  if (threadIdx.x < 13) bf3[threadIdx.x]=bias3[threadIdx.x];
  __syncthreads();
  int lane = threadIdx.x & 63, wv = threadIdx.x >> 6;
  int tl = lane >> 2, cq = lane & 3;
  int t = blockIdx.x*64 + wv*16 + tl;
  const unsigned short* xrow = c2 + (size_t)t*256 + cq*64;
  float acc[13];
  #pragma unroll
  for (int o=0;o<13;o++) acc[o]=0.f;
  for (int c=0;c<64;c+=8){
    short8 xv = *(const short8*)(xrow + c);
    float xs[8];
    #pragma unroll
    for (int u=0;u<8;u++) xs[u]=bf2f((unsigned short)xv[u]);
    #pragma unroll
    for (int o=0;o<13;o++){
      const float* wr = wf + o*256 + cq*64 + c;
      #pragma unroll
      for (int u=0;u<8;u++) acc[o] += wr[u]*xs[u];
    }
  }
  #pragma unroll
  for (int o=0;o<13;o++){
    acc[o] += __shfl_xor(acc[o], 1, 64);
    acc[o] += __shfl_xor(acc[o], 2, 64);
  }
  if (cq==0){
    int b = t >> 12, n = t & 4095;
    #pragma unroll
    for (int o=0;o<13;o++)
      outp[((size_t)b*13 + o)*NP + n] = acc[o] + bf3[o];
  }
}

// ---------------- launch ----------------
extern "C" void kernel_launch(void* const* d_in, const int* in_sizes, int n_in,
                              void* d_out, int out_size, void* d_ws, size_t ws_size,
                              hipStream_t stream) {
  (void)in_sizes; (void)n_in; (void)out_size; (void)d_ws; (void)ws_size;
  const float* in      = (const float*)d_in[0];
  const float* emb_w1  = (const float*)d_in[1];
  const float* emb_s1  = (const float*)d_in[2];
  const float* emb_b1  = (const float*)d_in[3];
  const float* emb_w2  = (const float*)d_in[4];
  const float* emb_s2  = (const float*)d_in[5];
  const float* emb_b2  = (const float*)d_in[6];
  const float* blk_wq  = (const float*)d_in[7];
  const float* blk_wk  = (const float*)d_in[8];
  const float* blk_wv  = (const float*)d_in[9];
  const float* blk_wpos= (const float*)d_in[10];
  const float* blk_wo  = (const float*)d_in[11];
  const float* blk_s   = (const float*)d_in[12];
  const float* blk_b   = (const float*)d_in[13];
  const float* fuse_w  = (const float*)d_in[14];
  const float* fuse_s  = (const float*)d_in[15];
  const float* fuse_b  = (const float*)d_in[16];
  const float* cls_w1  = (const float*)d_in[17];
  const float* cls_b1  = (const float*)d_in[18];
  const float* cls_s1  = (const float*)d_in[19];
  const float* cls_sh1 = (const float*)d_in[20];
  const float* cls_w2  = (const float*)d_in[21];
  const float* cls_b2  = (const float*)d_in[22];
  const float* cls_s2  = (const float*)d_in[23];
  const float* cls_sh2 = (const float*)d_in[24];
  const float* cls_w3  = (const float*)d_in[25];
  const float* cls_b3  = (const float*)d_in[26];

  // byte offsets into g_scratch
  const unsigned MB = 1u<<20, KB = 1024u;
  const unsigned OFF_IDX   = 0;                 // 1 MB   int idx[T][16]
  const unsigned OFF_WQ    = 1*MB;              // 96 KB  bf16 (3,128,128)
  const unsigned OFF_WK    = 1*MB + 128*KB;     // 96 KB
  const unsigned OFF_WV    = 1*MB + 256*KB;     // 96 KB
  const unsigned OFF_WO    = 1*MB + 384*KB;     // 96 KB
  const unsigned OFF_WEMB2 = 1*MB + 512*KB;     // 32 KB  bf16 (128,128)
  const unsigned OFF_WFUSE = 1*MB + 576*KB;     // 768 KB bf16 (1024,384)
  const unsigned OFF_WW1   = 3*MB;              // 1 MB   bf16 (512,1024) x-half
  const unsigned OFF_WW2   = 4*MB;              // 256 KB bf16 (256,512)
  const unsigned OFF_X1    = 5*MB;              // 4 MB   bf16 (T,128)
  const unsigned OFF_X0    = 9*MB;              // 4 MB   bf16 (T,128)
  const unsigned OFF_XCAT  = 13*MB;             // 12 MB  bf16 (T,384)
  const unsigned OFF_QB    = 25*MB;             // 4 MB
  const unsigned OFF_KB    = 29*MB;             // 4 MB
  const unsigned OFF_VB    = 33*MB;             // 4 MB
  const unsigned OFF_AGG   = 37*MB;             // 4 MB
  const unsigned OFF_XF    = 41*MB;             // 32 MB  bf16 (T,1024)
  const unsigned OFF_C1    = 73*MB;             // 16 MB  bf16 (T,512)
  const unsigned OFF_C2    = 89*MB;             // 8 MB   bf16 (T,256)
  const unsigned OFF_G     = 97*MB;             // 32 KB  f32 (B,2048)
  const unsigned OFF_GB    = 97*MB + 64*KB;     // 8 KB   f32 (B,512)
  const unsigned OFF_GP    = 97*MB + 128*KB;    // 256 KB f32 pool partials
  const unsigned OFF_THR   = 97*MB + 512*KB;    // 64 KB  f32 thr[T]
  const unsigned OFF_PD    = 98*MB;             // 16 MB  f32 knn bound vals / p2 dists
  const unsigned OFF_PI    = 114*MB;            // 16 MB  int knn idx (p2)
  float* outp = (float*)d_out;                  // (B,13,N) f32

  // 0: fused weight conversion prepass (fp32 -> bf16 into scratch)
  CvtArgs ca;
  ca.src[0]=emb_w2;  ca.dstOff[0]=OFF_WEMB2; ca.n[0]=128*128;
  ca.src[1]=blk_wq;  ca.dstOff[1]=OFF_WQ;    ca.n[1]=3*128*128;
  ca.src[2]=blk_wk;  ca.dstOff[2]=OFF_WK;    ca.n[2]=3*128*128;
  ca.src[3]=blk_wv;  ca.dstOff[3]=OFF_WV;    ca.n[3]=3*128*128;
  ca.src[4]=blk_wo;  ca.dstOff[4]=OFF_WO;    ca.n[4]=3*128*128;
  ca.src[5]=fuse_w;  ca.dstOff[5]=OFF_WFUSE; ca.n[5]=1024*384;
  ca.src[6]=cls_w2;  ca.dstOff[6]=OFF_WW2;   ca.n[6]=256*512;
  ca.src[7]=cls_w1;  ca.dstOff[7]=OFF_WW1;   ca.n[7]=512*1024;
  cvt_all<<<dim3(64,8), 256, 0, stream>>>(ca);

  // 1-4: KNN (cheap-threshold two-pass)
  knn_p1<<<dim3(16,16,4), 256, 0, stream>>>(in, OFF_PD);
  knn_thr<<<dim3(64), 256, 0, stream>>>(OFF_PD, OFF_THR);
  knn_p2<<<dim3(16,16,4), 256, 0, stream>>>(in, OFF_THR, OFF_PD, OFF_PI);
  knn_mrg<<<dim3(256), 64, 0, stream>>>(OFF_PD, OFF_PI, OFF_IDX);
  // 5-6: embedding
  emb1_kernel<<<dim3(64,4), 256, 0, stream>>>(in, emb_w1, emb_s1, emb_b1, OFF_X1);
  gemm_small_lds<EPI_RELU_SB,false><<<dim3(2,128,1), 128, 0, stream>>>(
      OFF_WEMB2, OFF_WEMB2, OFF_WEMB2, OFF_X0, OFF_X0, OFF_X0,
      OFF_X1, 128, 0, 128, 0, emb_s2, emb_b2,
      nullptr, 0, 0, 0, 0, 0, 128, 128);
  // 7-9: transformer blocks
  for (int i=0;i<3;i++){
    unsigned wq = OFF_WQ + i*32768, wk = OFF_WK + i*32768;
    unsigned wv = OFF_WV + i*32768, wo = OFF_WO + i*32768;
    const float* wp = blk_wpos + i*128*3;
    const float* si = blk_s + i*128;
    const float* bi = blk_b + i*128;
    unsigned XiOff = (i==0) ? OFF_X0 : OFF_XCAT;
    int Xs = (i==0) ? 128 : 384;
    int Xo = (i==0) ? 0 : (i-1)*128;
    gemm_small_lds<EPI_PLAIN,false><<<dim3(2,128,3), 128, 0, stream>>>(
        wq, wk, wv, OFF_QB, OFF_KB, OFF_VB,
        XiOff, Xs, Xo, 128, 0, nullptr, nullptr,
        nullptr, 0, 0, 0, 0, 0, 128, 128);
    attn_kernel<<<dim3(1024), 256, 0, stream>>>(OFF_QB, OFF_KB, OFF_VB, OFF_IDX, in, wp, OFF_AGG);
    gemm_small_lds<EPI_RES,false><<<dim3(2,128,1), 128, 0, stream>>>(
        wo, wo, wo, OFF_XCAT, OFF_XCAT, OFF_XCAT,
        OFF_AGG, 128, 0, 384, i*128, si, bi,
        nullptr, 0, 0, XiOff, Xs, Xo, 128, 128);
  }
  // 10: fuse (leaky relu), LDS-staged + swizzled
  gemm_lds<EPI_LEAKY,false><<<dim3(8,128,1), 256, 0, stream>>>(
      OFF_WFUSE, OFF_WFUSE, OFF_WFUSE, OFF_XF, OFF_XF, OFF_XF,
      OFF_XCAT, 384, 0, 1024, 0, fuse_s, fuse_b,
      nullptr, 0, 0, 0, 0, 0, 384, 384);
  // 11-13: pooling (two-stage) + broadcast-g term of cls1 (fp32)
  pool_part<<<dim3(512), 256, 0, stream>>>(OFF_XF, OFF_GP);
  pool_final<<<dim3(4), 256, 0, stream>>>(OFF_GP, OFF_G);
  gterm_kernel<<<dim3(32), 256, 0, stream>>>(cls_w1, cls_b1, OFF_G, OFF_GB);
  // 14: cls1 (K=1024 x-half of W1; gb = W1[:,1024:]@g + bias1 as extra)
  gemm_lds<EPI_CLS,false><<<dim3(4,128,1), 256, 0, stream>>>(
      OFF_WW1, OFF_WW1, OFF_WW1, OFF_C1, OFF_C1, OFF_C1,
      OFF_XF, 1024, 0, 512, 0, cls_s1, cls_sh1,
      nullptr, OFF_GB, 512, 0, 0, 0, 1024, 1024);
  // 15: cls2 (K=512), LDS-staged
  gemm_lds<EPI_CLS,true><<<dim3(2,128,1), 256, 0, stream>>>(
      OFF_WW2, OFF_WW2, OFF_WW2, OFF_C2, OFF_C2, OFF_C2,
      OFF_C1, 512, 0, 256, 0, cls_s2, cls_sh2,
      cls_b2, 0, 0, 0, 0, 0, 512, 512);
  // 16: cls3 -> d_out (fp32)
  cls3_kernel<<<dim3(256), 256, 0, stream>>>(OFF_C2, cls_w3, cls_b3, outp);
}